// Round 1
// baseline (767.108 us; speedup 1.0000x reference)
//
#include <hip/hip_runtime.h>

#define HG 256
#define WGD 256
#define NN (HG*WGD)
#define NL 6

typedef _Float16 f16;
typedef _Float16 f16x8 __attribute__((ext_vector_type(8)));
typedef float f32x4 __attribute__((ext_vector_type(4)));

__device__ __forceinline__ void gload_lds16(const f16* g, f16* lds) {
  __builtin_amdgcn_global_load_lds(
      (const __attribute__((address_space(1))) unsigned int*)g,
      (__attribute__((address_space(3))) unsigned int*)lds, 16, 0, 0);
}

// C[M, Nout] = A[M, K(=KK)] @ Bt[Nout, KK]^T, A/Bt fp16, fp32 accum, f16 out.
// EPI: 0 = plain store; 1 = +bias[col] + deg(row)*v2[col], relu; 2 = +bias[col]
template<int KK, int EPI>
__global__ __launch_bounds__(256) void gemm_bt(
    const f16* __restrict__ A, int lda,
    const f16* __restrict__ Bt,
    f16* __restrict__ C, int ldc,
    const float* __restrict__ bias,
    const float* __restrict__ v2)
{
  __shared__ f16 As[128*64];
  __shared__ f16 Bs[128*64];
  const int tid  = threadIdx.x;
  const int lane = tid & 63;
  const int w    = tid >> 6;       // wave 0..3
  const int wm   = w >> 1, wn = w & 1;
  const int mbase = blockIdx.x * 128;
  const int nbase = blockIdx.y * 128;

  f32x4 acc[4][4];
#pragma unroll
  for (int a=0;a<4;a++)
#pragma unroll
    for (int b=0;b<4;b++) acc[a][b] = (f32x4){0.f,0.f,0.f,0.f};

  const int r8 = lane >> 3;        // 0..7
  const int c8 = (lane & 7) * 8;   // 0..56 elems

  for (int kt = 0; kt < KK/64; ++kt) {
    const f16* Ab = A  + (size_t)(mbase + w*32)*lda + kt*64;
    const f16* Bb = Bt + (size_t)(nbase + w*32)*KK  + kt*64;
#pragma unroll
    for (int i=0;i<4;i++) {
      gload_lds16(Ab + (size_t)(i*8 + r8)*lda + c8, &As[(w*32+i*8)*64]);
      gload_lds16(Bb + (size_t)(i*8 + r8)*KK  + c8, &Bs[(w*32+i*8)*64]);
    }
    __syncthreads();
#pragma unroll
    for (int ks=0; ks<2; ++ks) {
      f16x8 af[4], bf[4];
#pragma unroll
      for (int fm=0; fm<4; ++fm)
        af[fm] = *(const f16x8*)&As[(wm*64 + fm*16 + (lane&15))*64 + ks*32 + (lane>>4)*8];
#pragma unroll
      for (int fn=0; fn<4; ++fn)
        bf[fn] = *(const f16x8*)&Bs[(wn*64 + fn*16 + (lane&15))*64 + ks*32 + (lane>>4)*8];
#pragma unroll
      for (int fm=0; fm<4; ++fm)
#pragma unroll
        for (int fn=0; fn<4; ++fn)
          acc[fm][fn] = __builtin_amdgcn_mfma_f32_16x16x32_f16(af[fm], bf[fn], acc[fm][fn], 0,0,0);
    }
    __syncthreads();
  }

  const int row0 = mbase + wm*64 + (lane>>4)*4;
  const int col0 = nbase + wn*64 + (lane&15);
#pragma unroll
  for (int fm=0; fm<4; ++fm) {
#pragma unroll
    for (int fn=0; fn<4; ++fn) {
      const int col = col0 + fn*16;
#pragma unroll
      for (int r=0;r<4;r++) {
        int row = row0 + fm*16 + r;
        float v = acc[fm][fn][r];
        if (EPI==1) {
          int i = row >> 8, j = row & 255;
          float deg = (float)((i>0)+(i<255)+(j>0)+(j<255));
          v += bias[col] + deg * v2[col];
          v = fmaxf(v, 0.f);
        } else if (EPI==2) {
          v += bias[col];
        }
        C[(size_t)row*ldc + col] = (f16)v;
      }
    }
  }
}

// R[n] = sum over valid dirs d of relu(P[src_d] + Q[n] + cvec_d + (si/256)*wsi + (sj/256)*wsj)
// PQ layout [N,512]: cols 0..255 = P, 256..511 = Q. Writes R into HR cols 256..511.
__global__ __launch_bounds__(256) void edge_fuse(
    const f16* __restrict__ PQ, f16* __restrict__ HR,
    const float* __restrict__ cvec, const float* __restrict__ wsi_,
    const float* __restrict__ wsj_)
{
  const int t  = threadIdx.x;
  const int ln = t >> 5, ch = t & 31;
  const int n  = blockIdx.x*8 + ln;
  const int i  = n >> 8, j = n & 255;
  const int co = ch*8;

  float q[8];
  { f16x8 qv = *(const f16x8*)&PQ[(size_t)n*512 + 256 + co];
#pragma unroll
    for (int e=0;e<8;e++) q[e] = (float)qv[e]; }
  float wi[8], wj[8];
#pragma unroll
  for (int e=0;e<8;e++){ wi[e]=wsi_[co+e]; wj[e]=wsj_[co+e]; }
  float acc[8];
#pragma unroll
  for (int e=0;e<8;e++) acc[e]=0.f;

  const int DI[4] = {-1,1,0,0};
  const int DJ[4] = {0,0,-1,1};
#pragma unroll
  for (int d=0; d<4; ++d) {
    int si = i - DI[d], sj = j - DJ[d];
    if (si>=0 && si<HG && sj>=0 && sj<WGD) {
      int s = si*WGD + sj;
      f16x8 pv = *(const f16x8*)&PQ[(size_t)s*512 + co];
      float fsi = si * (1.f/HG), fsj = sj * (1.f/WGD);
#pragma unroll
      for (int e=0;e<8;e++) {
        float v = (float)pv[e] + q[e] + cvec[d*256+co+e] + fsi*wi[e] + fsj*wj[e];
        acc[e] += fmaxf(v, 0.f);
      }
    }
  }
  f16x8 outv;
#pragma unroll
  for (int e=0;e<8;e++) outv[e] = (f16)acc[e];
  *(f16x8*)&HR[(size_t)n*512 + 256 + co] = outv;
}

__global__ __launch_bounds__(256) void init_h(
    const int* __restrict__ grid, const float* __restrict__ nW,
    const float* __restrict__ nb, f16* __restrict__ HR)
{
  int idx = blockIdx.x*256 + threadIdx.x;   // N*32
  int n = idx >> 5, co = (idx & 31)*8;
  float g = (float)grid[n];
  f16x8 h;
#pragma unroll
  for (int e=0;e<8;e++) h[e] = (f16)(g*nW[co+e] + nb[co+e]);
  *(f16x8*)&HR[(size_t)n*512 + co] = h;
}

__global__ __launch_bounds__(256) void out_head(
    const f16* __restrict__ HR, const float* __restrict__ Wp,
    const float* __restrict__ ob, float* __restrict__ out)
{
  int t = threadIdx.x;
  int c = t & 15, lnode = t >> 4;
  int n = blockIdx.x*16 + lnode;
  float acc = 0.f;
  for (int k8=0;k8<32;k8++){
    f16x8 hv = *(const f16x8*)&HR[(size_t)n*512 + k8*8];
#pragma unroll
    for (int e=0;e<8;e++) acc += (float)hv[e]*Wp[(k8*8+e)*16 + c];
  }
  if (c < 10) out[(size_t)n*10 + c] = acc + ob[c];
}

// ---- prep kernels (weights repack / fold), run once per call ----
__global__ __launch_bounds__(256) void prep_btA(const float* __restrict__ mW1, f16* __restrict__ BtA){
  int idx = blockIdx.x*256+threadIdx.x;   // 6*512*256
  int l = idx >> 17;
  int r = idx & 131071;
  int jp = r >> 8;
  int k = r & 255;
  int srow = (jp < 256) ? k : 256 + k;
  int scol = jp & 255;
  BtA[idx] = (f16)mW1[((size_t)l*516 + srow)*256 + scol];
}

__global__ __launch_bounds__(256) void prep_btB(const float* __restrict__ mW2,
                                                const float* __restrict__ uW1,
                                                f16* __restrict__ BtB){
  int idx = blockIdx.x*256+threadIdx.x;   // 6*512*256, order l,k,jp
  int jp = idx & 255;
  int k = (idx >> 8) & 511;
  int l = idx >> 17;
  float v;
  if (k < 256) {
    v = uW1[((size_t)l*512 + k)*256 + jp];
  } else {
    int rr = k - 256;
    v = 0.f;
    for (int t2=0;t2<256;t2++)
      v += mW2[((size_t)l*256+rr)*256+t2] * uW1[((size_t)l*512+256+t2)*256+jp];
  }
  BtB[((size_t)l*256 + jp)*512 + k] = (f16)v;
}

__global__ __launch_bounds__(256) void prep_btC(const float* __restrict__ uW2, f16* __restrict__ BtC){
  int idx = blockIdx.x*256+threadIdx.x;   // 6*256*256, order l,k,jp
  int jp = idx & 255;
  int k = (idx >> 8) & 255;
  int l = idx >> 16;
  BtC[((size_t)l*256 + jp)*256 + k] = (f16)uW2[((size_t)l*256 + k)*256 + jp];
}

__global__ __launch_bounds__(256) void prep_vec(
    const float* __restrict__ mW1, const float* __restrict__ mb1,
    const float* __restrict__ mb2, const float* __restrict__ uW1,
    float* __restrict__ cvec, float* __restrict__ wsi_,
    float* __restrict__ wsj_, float* __restrict__ v2)
{
  int idx = blockIdx.x*256+threadIdx.x;   // 6*256
  int j = idx & 255, l = idx >> 8;
  const float* base = mW1 + (size_t)l*516*256;
  float w512 = base[512*256 + j], w513 = base[513*256 + j];
  float b1 = mb1[l*256 + j];
  const int DI[4] = {-1,1,0,0};
  const int DJ[4] = {0,0,-1,1};
  for (int d=0;d<4;d++)
    cvec[(l*4+d)*256 + j] = (float)DI[d]*w512 + (float)DJ[d]*w513 + b1;
  wsi_[idx] = base[514*256 + j];
  wsj_[idx] = base[515*256 + j];
  float s = 0.f;
  for (int t2=0;t2<256;t2++)
    s += mb2[l*256+t2] * uW1[((size_t)l*512+256+t2)*256 + j];
  v2[idx] = s;
}

__global__ __launch_bounds__(256) void prep_outW(const float* __restrict__ oW, float* __restrict__ Wp){
  int idx = blockIdx.x*256+threadIdx.x;   // 4096
  int k = idx >> 4, c = idx & 15;
  Wp[idx] = (c < 10) ? oW[k*10 + c] : 0.f;
}

extern "C" void kernel_launch(void* const* d_in, const int* in_sizes, int n_in,
                              void* d_out, int out_size, void* d_ws, size_t ws_size,
                              hipStream_t stream)
{
  const int*   grid = (const int*)  d_in[0];
  const float* nW   = (const float*)d_in[3];
  const float* nb   = (const float*)d_in[4];
  const float* mW1  = (const float*)d_in[5];
  const float* mb1  = (const float*)d_in[6];
  const float* mW2  = (const float*)d_in[7];
  const float* mb2  = (const float*)d_in[8];
  const float* uW1  = (const float*)d_in[9];
  const float* ub1  = (const float*)d_in[10];
  const float* uW2  = (const float*)d_in[11];
  const float* ub2  = (const float*)d_in[12];
  const float* oW   = (const float*)d_in[13];
  const float* ob   = (const float*)d_in[14];
  float* out = (float*)d_out;

  char* ws = (char*)d_ws;
  f16* HR  = (f16*)(ws);                         // [N,512] f16: cols 0..255 = h, 256..511 = R
  f16* PQ  = (f16*)(ws + 67108864);              // [N,512] f16: P | Q  (U aliases first half)
  f16* U   = PQ;                                 // [N,256] f16
  f16* BtA = (f16*)(ws + 134217728);             // 6*[512,256]
  f16* BtB = (f16*)(ws + 134217728 + 1572864);   // 6*[256,512]
  f16* BtC = (f16*)(ws + 134217728 + 2*1572864); // 6*[256,256]
  float* cvec = (float*)(ws + 134217728 + 2*1572864 + 786432);
  float* wsi_ = cvec + 6*4*256;
  float* wsj_ = wsi_ + 6*256;
  float* v2   = wsj_ + 6*256;
  float* Wp   = v2 + 6*256;

  prep_btA <<<3072,256,0,stream>>>(mW1, BtA);
  prep_btB <<<3072,256,0,stream>>>(mW2, uW1, BtB);
  prep_btC <<<1536,256,0,stream>>>(uW2, BtC);
  prep_vec <<<6,   256,0,stream>>>(mW1, mb1, mb2, uW1, cvec, wsi_, wsj_, v2);
  prep_outW<<<16,  256,0,stream>>>(oW, Wp);
  init_h   <<<8192,256,0,stream>>>(grid, nW, nb, HR);

  for (int l=0;l<NL;l++){
    // PQ = h @ [W1a | W1b]   (N x 256) @ (256 x 512)
    gemm_bt<256,0><<<dim3(512,4),256,0,stream>>>(HR, 512, BtA + (size_t)l*512*256, PQ, 512, nullptr, nullptr);
    // R[n] = sum_d relu(P[src]+Q[n]+edgebias)
    edge_fuse<<<8192,256,0,stream>>>(PQ, HR, cvec + l*1024, wsi_ + l*256, wsj_ + l*256);
    // U = relu(h@uW1a + R@W2u + ub1 + deg*v2)   ([h|R] is HR with K=512)
    gemm_bt<512,1><<<dim3(512,2),256,0,stream>>>(HR, 512, BtB + (size_t)l*256*512, U, 256, ub1 + l*256, v2 + l*256);
    // h_new = U @ uW2 + ub2  -> back into HR cols 0..255
    gemm_bt<256,2><<<dim3(512,2),256,0,stream>>>(U, 256, BtC + (size_t)l*256*256, HR, 512, ub2 + l*256, nullptr);
  }
  out_head<<<4096,256,0,stream>>>(HR, Wp, ob, out);
}

// Round 2
// 668.566 us; speedup vs baseline: 1.1474x; 1.1474x over previous
//
#include <hip/hip_runtime.h>

#define HG 256
#define WGD 256
#define NN (HG*WGD)
#define NL 6

typedef _Float16 f16;
typedef _Float16 f16x8 __attribute__((ext_vector_type(8)));
typedef float f32x4 __attribute__((ext_vector_type(4)));

__device__ __forceinline__ void gload_lds16(const f16* g, f16* lds) {
  __builtin_amdgcn_global_load_lds(
      (const __attribute__((address_space(1))) unsigned int*)g,
      (__attribute__((address_space(3))) unsigned int*)lds, 16, 0, 0);
}

// C[M,N] = A[M,KK] @ Bt[N,KK]^T  (f16 in, f32 accum, f16 out), z-batched.
// EPI: 0 plain | 1 +bias[col]+deg(row)*v2[col], relu | 2 +bias[col]
//      3 +bias[col]+deg*v2[col]+g[row]*avec[col], relu   (layer-1 update)
template<int KK, int EPI>
__global__ __launch_bounds__(256) void gemm_bt(
    const f16* __restrict__ A, int lda, size_t asb,
    const f16* __restrict__ Bt, int ldb, size_t bsb,
    f16* __restrict__ C, int ldc, size_t csb,
    const float* __restrict__ bias,
    const float* __restrict__ v2,
    const float* __restrict__ avec,
    const int* __restrict__ gridv)
{
  A  += blockIdx.z * asb;
  Bt += blockIdx.z * bsb;
  C  += blockIdx.z * csb;

  __shared__ f16 As[128*64];
  __shared__ f16 Bs[128*64];
  const int tid  = threadIdx.x;
  const int lane = tid & 63;
  const int w    = tid >> 6;
  const int wm   = w >> 1, wn = w & 1;
  const int mbase = blockIdx.x * 128;
  const int nbase = blockIdx.y * 128;

  f32x4 acc[4][4];
#pragma unroll
  for (int a=0;a<4;a++)
#pragma unroll
    for (int b=0;b<4;b++) acc[a][b] = (f32x4){0.f,0.f,0.f,0.f};

  const int r8 = lane >> 3;
  const int c8 = (lane & 7) * 8;

  for (int kt = 0; kt < KK/64; ++kt) {
    const f16* Ab = A  + (size_t)(mbase + w*32)*lda + kt*64;
    const f16* Bb = Bt + (size_t)(nbase + w*32)*ldb + kt*64;
#pragma unroll
    for (int i=0;i<4;i++) {
      gload_lds16(Ab + (size_t)(i*8 + r8)*lda + c8, &As[(w*32+i*8)*64]);
      gload_lds16(Bb + (size_t)(i*8 + r8)*ldb + c8, &Bs[(w*32+i*8)*64]);
    }
    __syncthreads();
#pragma unroll
    for (int ks=0; ks<2; ++ks) {
      f16x8 af[4], bf[4];
#pragma unroll
      for (int fm=0; fm<4; ++fm)
        af[fm] = *(const f16x8*)&As[(wm*64 + fm*16 + (lane&15))*64 + ks*32 + (lane>>4)*8];
#pragma unroll
      for (int fn=0; fn<4; ++fn)
        bf[fn] = *(const f16x8*)&Bs[(wn*64 + fn*16 + (lane&15))*64 + ks*32 + (lane>>4)*8];
#pragma unroll
      for (int fm=0; fm<4; ++fm)
#pragma unroll
        for (int fn=0; fn<4; ++fn)
          acc[fm][fn] = __builtin_amdgcn_mfma_f32_16x16x32_f16(af[fm], bf[fn], acc[fm][fn], 0,0,0);
    }
    __syncthreads();
  }

  const int row0 = mbase + wm*64 + (lane>>4)*4;
  const int col0 = nbase + wn*64 + (lane&15);
#pragma unroll
  for (int fm=0; fm<4; ++fm) {
#pragma unroll
    for (int fn=0; fn<4; ++fn) {
      const int col = col0 + fn*16;
#pragma unroll
      for (int r=0;r<4;r++) {
        int row = row0 + fm*16 + r;
        float v = acc[fm][fn][r];
        if (EPI==1 || EPI==3) {
          int i = row >> 8, j = row & 255;
          float deg = (float)((i>0)+(i<255)+(j>0)+(j<255));
          v += bias[col] + deg * v2[col];
          if (EPI==3) v += (float)gridv[row] * avec[col];
          v = fmaxf(v, 0.f);
        } else if (EPI==2) {
          v += bias[col];
        }
        C[(size_t)row*ldc + col] = (f16)v;
      }
    }
  }
}

// R[n] = sum over valid dirs of relu(P[src]+Q[n]+cvec_d+(si/256)*wsi+(sj/256)*wsj)
// PQ [N,512]: cols 0..255 = P, 256..511 = Q.  Writes R into UR cols 256..511.
__global__ __launch_bounds__(256) void edge_fuse(
    const f16* __restrict__ PQ, f16* __restrict__ UR,
    const float* __restrict__ cvec, const float* __restrict__ wsi_,
    const float* __restrict__ wsj_)
{
  const int t  = threadIdx.x;
  const int ln = t >> 5, ch = t & 31;
  const int n  = blockIdx.x*8 + ln;
  const int i  = n >> 8, j = n & 255;
  const int co = ch*8;

  float q[8];
  { f16x8 qv = *(const f16x8*)&PQ[(size_t)n*512 + 256 + co];
#pragma unroll
    for (int e=0;e<8;e++) q[e] = (float)qv[e]; }
  float wi[8], wj[8];
#pragma unroll
  for (int e=0;e<8;e++){ wi[e]=wsi_[co+e]; wj[e]=wsj_[co+e]; }
  float acc[8];
#pragma unroll
  for (int e=0;e<8;e++) acc[e]=0.f;

  const int DI[4] = {-1,1,0,0};
  const int DJ[4] = {0,0,-1,1};
#pragma unroll
  for (int d=0; d<4; ++d) {
    int si = i - DI[d], sj = j - DJ[d];
    if (si>=0 && si<HG && sj>=0 && sj<WGD) {
      int s = si*WGD + sj;
      f16x8 pv = *(const f16x8*)&PQ[(size_t)s*512 + co];
      float fsi = si * (1.f/HG), fsj = sj * (1.f/WGD);
#pragma unroll
      for (int e=0;e<8;e++) {
        float v = (float)pv[e] + q[e] + cvec[d*256+co+e] + fsi*wi[e] + fsj*wj[e];
        acc[e] += fmaxf(v, 0.f);
      }
    }
  }
  f16x8 outv;
#pragma unroll
  for (int e=0;e<8;e++) outv[e] = (f16)acc[e];
  *(f16x8*)&UR[(size_t)n*512 + 256 + co] = outv;
}

// PQ_1[n,c] = g[n]*pa[c] + pc[c]   (rank-1 layer-1 input)
__global__ __launch_bounds__(256) void pq1(
    const int* __restrict__ gridv, const float* __restrict__ pa,
    const float* __restrict__ pc, f16* __restrict__ PQ)
{
  int idx = blockIdx.x*256 + threadIdx.x;   // N*64
  int n = idx >> 6, co = (idx & 63)*8;
  float g = (float)gridv[n];
  f16x8 v;
#pragma unroll
  for (int e=0;e<8;e++) v[e] = (f16)(g*pa[co+e] + pc[co+e]);
  *(f16x8*)&PQ[(size_t)n*512 + co] = v;
}

// out[n,0..9] = U6[n,:] @ Wp2t^T + ob2  via MFMA, 1 wave = 16 nodes
__global__ __launch_bounds__(256) void out_mfma(
    const f16* __restrict__ U,        // lda 512
    const f16* __restrict__ Wp2t,     // [16][256]
    const float* __restrict__ ob2,
    float* __restrict__ out)
{
  int lane = threadIdx.x & 63;
  int wv   = threadIdx.x >> 6;
  int nbase = blockIdx.x*64 + wv*16;
  f32x4 acc = (f32x4){0.f,0.f,0.f,0.f};
  int r  = lane & 15;
  int kg = (lane >> 4) * 8;
  const f16* Up = U + (size_t)(nbase + r)*512 + kg;
  const f16* Bp = Wp2t + r*256 + kg;
#pragma unroll
  for (int kt=0; kt<8; ++kt) {
    f16x8 af = *(const f16x8*)(Up + kt*32);
    f16x8 bf = *(const f16x8*)(Bp + kt*32);
    acc = __builtin_amdgcn_mfma_f32_16x16x32_f16(af, bf, acc, 0,0,0);
  }
  int col = lane & 15;
  int row0 = (lane>>4)*4;
  if (col < 10) {
    float bo = ob2[col];
#pragma unroll
    for (int rr=0; rr<4; ++rr)
      out[(size_t)(nbase + row0 + rr)*10 + col] = acc[rr] + bo;
  }
}

// ---- prep kernels ----
// BtA[l][jp][k] = W1ab_l[k][jp]   ([512,256] f16 per layer)
__global__ __launch_bounds__(256) void prep_btA(const float* __restrict__ mW1, f16* __restrict__ BtA){
  int idx = blockIdx.x*256+threadIdx.x;   // 6*512*256
  int l = idx >> 17;
  int r = idx & 131071;
  int jp = r >> 8;
  int k = r & 255;
  int srow = (jp < 256) ? k : 256 + k;
  int scol = jp & 255;
  BtA[idx] = (f16)mW1[((size_t)l*516 + srow)*256 + scol];
}

// f16 cast of uW2 (row-major) and transposed-cast of uW1a
__global__ __launch_bounds__(256) void prep_casts(const float* __restrict__ uW2,
                                                  const float* __restrict__ uW1,
                                                  f16* __restrict__ uW2h,
                                                  f16* __restrict__ uW1aT){
  int idx = blockIdx.x*256+threadIdx.x;   // 6*256*256
  int l = idx >> 16; int k = (idx>>8)&255; int j = idx&255;
  uW2h[idx] = (f16)uW2[idx];
  uW1aT[((size_t)l*256 + j)*256 + k] = (f16)uW1[((size_t)l*512 + k)*256 + j];
}

// BtU[l][jp][256+r] = (mW2_l @ uW1b_l)^T  = W2u^T  (second half of BtU)
__global__ __launch_bounds__(256) void prep_w2ut(const float* __restrict__ mW2,
                                                 const float* __restrict__ uW1,
                                                 f16* __restrict__ BtU){
  int idx = blockIdx.x*256+threadIdx.x;   // 6*256*256: l, jp, r
  int l = idx >> 16; int jp = (idx>>8)&255; int rr = idx&255;
  float v = 0.f;
  for (int t2=0;t2<256;t2++)
    v += mW2[((size_t)l*256+rr)*256+t2] * uW1[((size_t)l*512+256+t2)*256+jp];
  BtU[((size_t)l*256+jp)*512 + 256 + rr] = (f16)v;
}

// per (l,j): cvec, wsi, wsj, v2, ubias (+avec for l==0)
__global__ __launch_bounds__(256) void prep_vecA(
    const float* __restrict__ mW1, const float* __restrict__ mb1,
    const float* __restrict__ mb2, const float* __restrict__ uW1,
    const float* __restrict__ ub1, const float* __restrict__ ub2,
    const float* __restrict__ nW,  const float* __restrict__ nb,
    float* __restrict__ cvec, float* __restrict__ wsi_,
    float* __restrict__ wsj_, float* __restrict__ v2,
    float* __restrict__ ubias, float* __restrict__ avec)
{
  int l = blockIdx.x, j = threadIdx.x;
  const float* base = mW1 + (size_t)l*516*256;
  float w512 = base[512*256 + j], w513 = base[513*256 + j];
  float b1 = mb1[l*256 + j];
  const int DI[4] = {-1,1,0,0};
  const int DJ[4] = {0,0,-1,1};
  for (int d=0;d<4;d++)
    cvec[(l*4+d)*256 + j] = (float)DI[d]*w512 + (float)DJ[d]*w513 + b1;
  wsi_[l*256+j] = base[514*256 + j];
  wsj_[l*256+j] = base[515*256 + j];
  float s = 0.f;
  for (int t2=0;t2<256;t2++)
    s += mb2[l*256+t2] * uW1[((size_t)l*512+256+t2)*256 + j];
  v2[l*256+j] = s;
  const float* prevb = (l > 0) ? (ub2 + (l-1)*256) : nb;
  float ub = 0.f;
  for (int k=0;k<256;k++)
    ub += prevb[k] * uW1[((size_t)l*512 + k)*256 + j];
  ubias[l*256+j] = ub1[l*256+j] + ub;
  if (l == 0) {
    float av = 0.f;
    for (int k=0;k<256;k++)
      av += nW[k] * uW1[(size_t)k*256 + j];
    avec[j] = av;
  }
}

// per (l,c in 0..511): pqb[l][c] for l>=1; pa/pc for l==0
__global__ __launch_bounds__(256) void prep_pqb(
    const float* __restrict__ mW1, const float* __restrict__ ub2,
    const float* __restrict__ nW,  const float* __restrict__ nb,
    float* __restrict__ pqb, float* __restrict__ pa, float* __restrict__ pc)
{
  int idx = blockIdx.x*256+threadIdx.x;   // 6*512
  int l = idx >> 9, c = idx & 511;
  const float* base = mW1 + (size_t)l*516*256;
  int rowoff = (c < 256) ? 0 : 256;
  int cc = c & 255;
  if (l == 0) {
    float sa = 0.f, sc = 0.f;
    for (int j=0;j<256;j++) {
      float wv = base[(size_t)(rowoff + j)*256 + cc];
      sa += nW[j]*wv; sc += nb[j]*wv;
    }
    pa[c] = sa; pc[c] = sc;
  } else {
    const float* pb = ub2 + (l-1)*256;
    float s = 0.f;
    for (int j=0;j<256;j++)
      s += pb[j] * base[(size_t)(rowoff + j)*256 + cc];
    pqb[l*512 + c] = s;
  }
}

// Wp2t[c][k] = sum_j uW2_6[k][j]*outW[j][c] (c<10), ob2
__global__ __launch_bounds__(256) void prep_out(
    const float* __restrict__ uW2, const float* __restrict__ ub2,
    const float* __restrict__ oW,  const float* __restrict__ ob,
    f16* __restrict__ Wp2t, float* __restrict__ ob2)
{
  int idx = blockIdx.x*256+threadIdx.x;   // 16*256
  int c = idx >> 8, k = idx & 255;
  float v = 0.f;
  if (c < 10) {
    for (int j=0;j<256;j++)
      v += uW2[(size_t)(5*256 + k)*256 + j] * oW[j*10 + c];
  }
  Wp2t[c*256 + k] = (f16)v;
  if (k == 0) {
    float s = 0.f;
    if (c < 10) {
      for (int j=0;j<256;j++)
        s += ub2[5*256 + j] * oW[j*10 + c];
      s += ob[c];
    }
    ob2[c] = s;
  }
}

extern "C" void kernel_launch(void* const* d_in, const int* in_sizes, int n_in,
                              void* d_out, int out_size, void* d_ws, size_t ws_size,
                              hipStream_t stream)
{
  const int*   gridv = (const int*) d_in[0];
  const float* nW   = (const float*)d_in[3];
  const float* nb   = (const float*)d_in[4];
  const float* mW1  = (const float*)d_in[5];
  const float* mb1  = (const float*)d_in[6];
  const float* mW2  = (const float*)d_in[7];
  const float* mb2  = (const float*)d_in[8];
  const float* uW1  = (const float*)d_in[9];
  const float* ub1  = (const float*)d_in[10];
  const float* uW2  = (const float*)d_in[11];
  const float* ub2  = (const float*)d_in[12];
  const float* oW   = (const float*)d_in[13];
  const float* ob   = (const float*)d_in[14];
  float* out = (float*)d_out;

  char* ws = (char*)d_ws;
  size_t off = 0;
  f16* URa  = (f16*)(ws + off); off += (size_t)NN*512*2;       // 64MB
  f16* URb  = (f16*)(ws + off); off += (size_t)NN*512*2;       // 64MB
  f16* BtA  = (f16*)(ws + off); off += 6*512*256*2;
  f16* BtPQ = (f16*)(ws + off); off += 6*512*256*2;            // slot 0 unused
  f16* BtU  = (f16*)(ws + off); off += 6*256*512*2;
  f16* uW2h = (f16*)(ws + off); off += 6*256*256*2;
  f16* uW1aT= (f16*)(ws + off); off += 6*256*256*2;
  f16* Wp2t = (f16*)(ws + off); off += 16*256*2;
  float* cvec = (float*)(ws + off); off += 6*4*256*4;
  float* wsi_ = (float*)(ws + off); off += 6*256*4;
  float* wsj_ = (float*)(ws + off); off += 6*256*4;
  float* v2   = (float*)(ws + off); off += 6*256*4;
  float* ubias= (float*)(ws + off); off += 6*256*4;
  float* pqb  = (float*)(ws + off); off += 6*512*4;            // slot 0 unused
  float* pa   = (float*)(ws + off); off += 512*4;
  float* pc   = (float*)(ws + off); off += 512*4;
  float* avec = (float*)(ws + off); off += 256*4;
  float* ob2  = (float*)(ws + off); off += 16*4;

  // ---- prep ----
  prep_btA  <<<3072,256,0,stream>>>(mW1, BtA);
  prep_casts<<<1536,256,0,stream>>>(uW2, uW1, uW2h, uW1aT);
  prep_w2ut <<<1536,256,0,stream>>>(mW2, uW1, BtU);
  prep_vecA <<<6,   256,0,stream>>>(mW1, mb1, mb2, uW1, ub1, ub2, nW, nb,
                                    cvec, wsi_, wsj_, v2, ubias, avec);
  prep_pqb  <<<12,  256,0,stream>>>(mW1, ub2, nW, nb, pqb, pa, pc);
  prep_out  <<<16,  256,0,stream>>>(uW2, ub2, oW, ob, Wp2t, ob2);

  // weight folds (batched over layers l=2..6 -> z=0..4):
  // BtPQ[l] = BtA[l] @ uW2h[l-1]^T   (M=512,N=256,K=256)
  gemm_bt<256,0><<<dim3(4,2,5),256,0,stream>>>(
      BtA + 131072, 256, 131072, uW2h, 256, 65536,
      BtPQ + 131072, 256, 131072, nullptr, nullptr, nullptr, nullptr);
  // BtU[l] first half = uW1aT[l] @ uW2h[l-1]^T  (M=256,N=256,K=256, ldc=512)
  gemm_bt<256,0><<<dim3(2,2,5),256,0,stream>>>(
      uW1aT + 65536, 256, 65536, uW2h, 256, 65536,
      BtU + 131072, 512, 131072, nullptr, nullptr, nullptr, nullptr);

  // ---- layer 1 (rank-1 input) ----
  pq1      <<<16384,256,0,stream>>>(gridv, pa, pc, URb);
  edge_fuse<<<8192, 256,0,stream>>>(URb, URa, cvec, wsi_, wsj_);
  // U1 = relu(R @ W2uT_0 + ubias0 + deg*v2_0 + g*avec): K=256, Bt = BtU[0]+256 (ldb 512)
  gemm_bt<256,3><<<dim3(512,2),256,0,stream>>>(
      URa + 256, 512, 0, BtU + 256, 512, 0, URa, 512, 0,
      ubias, v2, avec, gridv);

  // ---- layers 2..6 ----
  f16* cur = URa; f16* nxt = URb;
  for (int l=1;l<NL;l++){
    // PQ_l = U_{l-1} @ BtPQ[l]^T + pqb[l]   (K=256, Nout=512) -> nxt (full)
    gemm_bt<256,2><<<dim3(512,4),256,0,stream>>>(
        cur, 512, 0, BtPQ + (size_t)l*131072, 256, 0, nxt, 512, 0,
        pqb + l*512, nullptr, nullptr, nullptr);
    // R_l -> cur cols 256..511
    edge_fuse<<<8192,256,0,stream>>>(nxt, cur, cvec + l*1024, wsi_ + l*256, wsj_ + l*256);
    // U_l = relu([U_{l-1}|R_l] @ BtU[l]^T + ubias + deg*v2) -> nxt cols 0..255
    gemm_bt<512,1><<<dim3(512,2),256,0,stream>>>(
        cur, 512, 0, BtU + (size_t)l*131072, 512, 0, nxt, 512, 0,
        ubias + l*256, v2 + l*256, nullptr, nullptr);
    f16* t = cur; cur = nxt; nxt = t;
  }

  // out = U6 @ Wp2t^T + ob2
  out_mfma<<<1024,256,0,stream>>>(cur, Wp2t, ob2, out);
}

// Round 3
// 613.726 us; speedup vs baseline: 1.2499x; 1.0894x over previous
//
#include <hip/hip_runtime.h>

#define HG 256
#define WGD 256
#define NN (HG*WGD)
#define NL 6

typedef _Float16 f16;
typedef _Float16 f16x8 __attribute__((ext_vector_type(8)));
typedef float f32x4 __attribute__((ext_vector_type(4)));

__device__ __forceinline__ void gload_lds16(const f16* g, f16* lds) {
  __builtin_amdgcn_global_load_lds(
      (const __attribute__((address_space(1))) unsigned int*)g,
      (__attribute__((address_space(3))) unsigned int*)lds, 16, 0, 0);
}

// C[M,N] = A[M,KK] @ Bt[N,KK]^T  (f16 in, f32 accum, f16 out), z-batched.
// EPI: 0 plain | 1 +bias[col]+deg(row)*v2[col], relu | 2 +bias[col]
//      3 +bias[col]+deg*v2[col]+g[row]*avec[col], relu   (layer-1 update)
template<int KK, int EPI>
__global__ __launch_bounds__(256) void gemm_bt(
    const f16* __restrict__ A, int lda, size_t asb,
    const f16* __restrict__ Bt, int ldb, size_t bsb,
    f16* __restrict__ C, int ldc, size_t csb,
    const float* __restrict__ bias,
    const float* __restrict__ v2,
    const float* __restrict__ avec,
    const int* __restrict__ gridv)
{
  A  += blockIdx.z * asb;
  Bt += blockIdx.z * bsb;
  C  += blockIdx.z * csb;

  __shared__ f16 As[128*64];
  __shared__ f16 Bs[128*64];
  const int tid  = threadIdx.x;
  const int lane = tid & 63;
  const int w    = tid >> 6;
  const int wm   = w >> 1, wn = w & 1;
  const int mbase = blockIdx.x * 128;
  const int nbase = blockIdx.y * 128;

  f32x4 acc[4][4];
#pragma unroll
  for (int a=0;a<4;a++)
#pragma unroll
    for (int b=0;b<4;b++) acc[a][b] = (f32x4){0.f,0.f,0.f,0.f};

  const int r8 = lane >> 3;
  const int c8 = (lane & 7) * 8;

  for (int kt = 0; kt < KK/64; ++kt) {
    const f16* Ab = A  + (size_t)(mbase + w*32)*lda + kt*64;
    const f16* Bb = Bt + (size_t)(nbase + w*32)*ldb + kt*64;
#pragma unroll
    for (int i=0;i<4;i++) {
      gload_lds16(Ab + (size_t)(i*8 + r8)*lda + c8, &As[(w*32+i*8)*64]);
      gload_lds16(Bb + (size_t)(i*8 + r8)*ldb + c8, &Bs[(w*32+i*8)*64]);
    }
    __syncthreads();
#pragma unroll
    for (int ks=0; ks<2; ++ks) {
      f16x8 af[4], bf[4];
#pragma unroll
      for (int fm=0; fm<4; ++fm)
        af[fm] = *(const f16x8*)&As[(wm*64 + fm*16 + (lane&15))*64 + ks*32 + (lane>>4)*8];
#pragma unroll
      for (int fn=0; fn<4; ++fn)
        bf[fn] = *(const f16x8*)&Bs[(wn*64 + fn*16 + (lane&15))*64 + ks*32 + (lane>>4)*8];
#pragma unroll
      for (int fm=0; fm<4; ++fm)
#pragma unroll
        for (int fn=0; fn<4; ++fn)
          acc[fm][fn] = __builtin_amdgcn_mfma_f32_16x16x32_f16(af[fm], bf[fn], acc[fm][fn], 0,0,0);
    }
    __syncthreads();
  }

  const int row0 = mbase + wm*64 + (lane>>4)*4;
  const int col0 = nbase + wn*64 + (lane&15);
#pragma unroll
  for (int fm=0; fm<4; ++fm) {
#pragma unroll
    for (int fn=0; fn<4; ++fn) {
      const int col = col0 + fn*16;
#pragma unroll
      for (int r=0;r<4;r++) {
        int row = row0 + fm*16 + r;
        float v = acc[fm][fn][r];
        if (EPI==1 || EPI==3) {
          int i = row >> 8, j = row & 255;
          float deg = (float)((i>0)+(i<255)+(j>0)+(j<255));
          v += bias[col] + deg * v2[col];
          if (EPI==3) v += (float)gridv[row] * avec[col];
          v = fmaxf(v, 0.f);
        } else if (EPI==2) {
          v += bias[col];
        }
        C[(size_t)row*ldc + col] = (f16)v;
      }
    }
  }
}

// R[n] = sum over valid dirs of relu(P[src]+Q[n]+cvec_d+(si/256)*wsi+(sj/256)*wsj)
// R1=0: PQ [N,512] cols 0..255 = P, 256..511 = Q.
// R1=1: P/Q computed analytically: P[s][c]=g[s]*pa[c]+pc[c], Q[n][c]=g[n]*pa[256+c]+pc[256+c]
// Writes R into UR cols 256..511.
template<int R1>
__global__ __launch_bounds__(256) void edge_fuse(
    const f16* __restrict__ PQ, f16* __restrict__ UR,
    const float* __restrict__ cvec, const float* __restrict__ wsi_,
    const float* __restrict__ wsj_,
    const int* __restrict__ gridv, const float* __restrict__ pa,
    const float* __restrict__ pc)
{
  const int t  = threadIdx.x;
  const int ln = t >> 5, ch = t & 31;
  const int n  = blockIdx.x*8 + ln;
  const int i  = n >> 8, j = n & 255;
  const int co = ch*8;

  float q[8], pa0[8], pc0[8];
  if (R1) {
    float g = (float)gridv[n];
#pragma unroll
    for (int e=0;e<8;e++) {
      pa0[e] = pa[co+e]; pc0[e] = pc[co+e];
      q[e] = g*pa[256+co+e] + pc[256+co+e];
    }
  } else {
    f16x8 qv = *(const f16x8*)&PQ[(size_t)n*512 + 256 + co];
#pragma unroll
    for (int e=0;e<8;e++) q[e] = (float)qv[e];
  }
  float wi[8], wj[8];
#pragma unroll
  for (int e=0;e<8;e++){ wi[e]=wsi_[co+e]; wj[e]=wsj_[co+e]; }
  float acc[8];
#pragma unroll
  for (int e=0;e<8;e++) acc[e]=0.f;

  const int DI[4] = {-1,1,0,0};
  const int DJ[4] = {0,0,-1,1};
#pragma unroll
  for (int d=0; d<4; ++d) {
    int si = i - DI[d], sj = j - DJ[d];
    if (si>=0 && si<HG && sj>=0 && sj<WGD) {
      int s = si*WGD + sj;
      float fsi = si * (1.f/HG), fsj = sj * (1.f/WGD);
      float pvf[8];
      if (R1) {
        float gs = (float)gridv[s];
#pragma unroll
        for (int e=0;e<8;e++) pvf[e] = gs*pa0[e] + pc0[e];
      } else {
        f16x8 pv = *(const f16x8*)&PQ[(size_t)s*512 + co];
#pragma unroll
        for (int e=0;e<8;e++) pvf[e] = (float)pv[e];
      }
#pragma unroll
      for (int e=0;e<8;e++) {
        float v = pvf[e] + q[e] + cvec[d*256+co+e] + fsi*wi[e] + fsj*wj[e];
        acc[e] += fmaxf(v, 0.f);
      }
    }
  }
  f16x8 outv;
#pragma unroll
  for (int e=0;e<8;e++) outv[e] = (f16)acc[e];
  *(f16x8*)&UR[(size_t)n*512 + 256 + co] = outv;
}

// out[n,0..9] = U6[n,:] @ Wp2t^T + ob2  via MFMA, 1 wave = 16 nodes
__global__ __launch_bounds__(256) void out_mfma(
    const f16* __restrict__ U,        // lda 512
    const f16* __restrict__ Wp2t,     // [128][256], rows >=10 zero
    const float* __restrict__ ob2,
    float* __restrict__ out)
{
  int lane = threadIdx.x & 63;
  int wv   = threadIdx.x >> 6;
  int nbase = blockIdx.x*64 + wv*16;
  f32x4 acc = (f32x4){0.f,0.f,0.f,0.f};
  int r  = lane & 15;
  int kg = (lane >> 4) * 8;
  const f16* Up = U + (size_t)(nbase + r)*512 + kg;
  const f16* Bp = Wp2t + r*256 + kg;
#pragma unroll
  for (int kt=0; kt<8; ++kt) {
    f16x8 af = *(const f16x8*)(Up + kt*32);
    f16x8 bf = *(const f16x8*)(Bp + kt*32);
    acc = __builtin_amdgcn_mfma_f32_16x16x32_f16(af, bf, acc, 0,0,0);
  }
  int col = lane & 15;
  int row0 = (lane>>4)*4;
  if (col < 10) {
    float bo = ob2[col];
#pragma unroll
    for (int rr=0; rr<4; ++rr)
      out[(size_t)(nbase + row0 + rr)*10 + col] = acc[rr] + bo;
  }
}

// ---- prep: LDS-tiled 256x256 transpose-cast, z-batched ----
// dst[l][c][r] = (f16)src[l][r][c]; src rows stride 256 (f32), dst rows stride 256 (f16)
__global__ __launch_bounds__(256) void tcast256(
    const float* __restrict__ src, size_t sls,
    f16* __restrict__ dst, size_t dls)
{
  __shared__ float tbuf[32][33];
  const int l = blockIdx.z;
  const int bc = blockIdx.x*32;   // src col base
  const int br = blockIdx.y*32;   // src row base
  const int tx = threadIdx.x & 31, ty = threadIdx.x >> 5;   // ty 0..7
  const float* s = src + (size_t)l*sls;
  f16* d = dst + (size_t)l*dls;
#pragma unroll
  for (int rr=0; rr<4; ++rr)
    tbuf[ty+rr*8][tx] = s[(size_t)(br+ty+rr*8)*256 + bc+tx];
  __syncthreads();
#pragma unroll
  for (int rr=0; rr<4; ++rr)
    d[(size_t)(bc+ty+rr*8)*256 + br+tx] = (f16)tbuf[tx][ty+rr*8];
}

// plain f16 casts of uW2, mW2 (both 6*256*256 row-major)
__global__ __launch_bounds__(256) void castw(
    const float* __restrict__ uW2, const float* __restrict__ mW2,
    f16* __restrict__ uW2h, f16* __restrict__ mW2h)
{
  int idx = blockIdx.x*256+threadIdx.x;   // 393216
  uW2h[idx] = (f16)uW2[idx];
  mW2h[idx] = (f16)mW2[idx];
}

// oWTh[c][j] = oW[j][c] for c<10 else 0  ([128][256] f16)
__global__ __launch_bounds__(256) void prep_owt(const float* __restrict__ oW, f16* __restrict__ oWTh){
  int c = blockIdx.x, j = threadIdx.x;
  oWTh[c*256 + j] = (c < 10) ? (f16)oW[j*10 + c] : (f16)0.f;
}

// cvec / wsi / wsj (direct reads, no reduction)
__global__ __launch_bounds__(256) void prep_cw(
    const float* __restrict__ mW1, const float* __restrict__ mb1,
    float* __restrict__ cvec, float* __restrict__ wsi_, float* __restrict__ wsj_)
{
  int l = blockIdx.x, j = threadIdx.x;
  const float* base = mW1 + (size_t)l*516*256;
  float w512 = base[512*256 + j], w513 = base[513*256 + j];
  float b1 = mb1[l*256 + j];
  const int DI[4] = {-1,1,0,0};
  const int DJ[4] = {0,0,-1,1};
  for (int d=0;d<4;d++)
    cvec[(l*4+d)*256 + j] = (float)DI[d]*w512 + (float)DJ[d]*w513 + b1;
  wsi_[l*256+j] = base[514*256 + j];
  wsj_[l*256+j] = base[515*256 + j];
}

// v2[l][j] = mb2_l . uW1b_l[:,j];  ubias[l][j] = ub1 + prevb . uW1a_l[:,j];  avec (l=0)
// 4-way split-K, wave-coalesced over j, LDS reduce. grid 24 x 256.
__global__ __launch_bounds__(256) void prep_vecB(
    const float* __restrict__ mb2, const float* __restrict__ uW1,
    const float* __restrict__ ub1, const float* __restrict__ ub2,
    const float* __restrict__ nb,  const float* __restrict__ nW,
    float* __restrict__ v2, float* __restrict__ ubias, float* __restrict__ avec)
{
  __shared__ float red[3][4][64];
  int pr = threadIdx.x & 63, q = threadIdx.x >> 6;
  int pair = blockIdx.x*64 + pr;           // 6*256
  int l = pair >> 8, j = pair & 255;
  const float* prevb = l ? (ub2 + (l-1)*256) : nb;
  float s1=0.f, s2=0.f, s3=0.f;
  for (int t = q*64; t < q*64+64; ++t) {
    s1 += mb2[l*256+t] * uW1[((size_t)l*512+256+t)*256 + j];
    s2 += prevb[t]     * uW1[((size_t)l*512+t)*256 + j];
    if (l==0) s3 += nW[t] * uW1[(size_t)t*256 + j];
  }
  red[0][q][pr]=s1; red[1][q][pr]=s2; red[2][q][pr]=s3;
  __syncthreads();
  if (q==0) {
    float a = red[0][0][pr]+red[0][1][pr]+red[0][2][pr]+red[0][3][pr];
    float b = red[1][0][pr]+red[1][1][pr]+red[1][2][pr]+red[1][3][pr];
    v2[pair] = a;
    ubias[pair] = ub1[pair] + b;
    if (l==0) avec[j] = red[2][0][pr]+red[2][1][pr]+red[2][2][pr]+red[2][3][pr];
  }
}

// pqb[l][c] (l>=1) = ub2[l-1] . W1ab_l[:,c];  pa/pc for l==0. grid 48 x 256.
__global__ __launch_bounds__(256) void prep_pqb2(
    const float* __restrict__ mW1, const float* __restrict__ ub2,
    const float* __restrict__ nW,  const float* __restrict__ nb,
    float* __restrict__ pqb, float* __restrict__ pa, float* __restrict__ pc)
{
  __shared__ float red[2][4][64];
  int pr = threadIdx.x & 63, q = threadIdx.x >> 6;
  int pair = blockIdx.x*64 + pr;           // 6*512
  int l = pair >> 9, c = pair & 511;
  int rowoff = (c < 256) ? 0 : 256;
  int cc = c & 255;
  const float* base = mW1 + (size_t)l*516*256 + (size_t)rowoff*256 + cc;
  float s1=0.f, s2=0.f;
  if (l==0) {
    for (int j=q*64; j<q*64+64; ++j) { float wv = base[(size_t)j*256]; s1 += nW[j]*wv; s2 += nb[j]*wv; }
  } else {
    const float* pb = ub2 + (l-1)*256;
    for (int j=q*64; j<q*64+64; ++j) s1 += pb[j]*base[(size_t)j*256];
  }
  red[0][q][pr]=s1; red[1][q][pr]=s2;
  __syncthreads();
  if (q==0) {
    float a = red[0][0][pr]+red[0][1][pr]+red[0][2][pr]+red[0][3][pr];
    if (l==0) { pa[c]=a; pc[c]=red[1][0][pr]+red[1][1][pr]+red[1][2][pr]+red[1][3][pr]; }
    else pqb[pair] = a;
  }
}

// ob2[c] = ub2_5 . oW[:,c] + ob[c]
__global__ __launch_bounds__(256) void prep_ob2(
    const float* __restrict__ ub2, const float* __restrict__ oW,
    const float* __restrict__ ob, float* __restrict__ ob2)
{
  __shared__ float red[16][16];
  int c = threadIdx.x >> 4, jg = threadIdx.x & 15;
  float s = 0.f;
  if (c < 10)
    for (int j=jg*16; j<jg*16+16; ++j) s += ub2[5*256+j]*oW[j*10+c];
  red[c][jg] = s;
  __syncthreads();
  if (jg==0) {
    float a=0.f;
    for (int t2=0;t2<16;t2++) a += red[c][t2];
    ob2[c] = (c < 10) ? a + ob[c] : 0.f;
  }
}

extern "C" void kernel_launch(void* const* d_in, const int* in_sizes, int n_in,
                              void* d_out, int out_size, void* d_ws, size_t ws_size,
                              hipStream_t stream)
{
  const int*   gridv = (const int*) d_in[0];
  const float* nW   = (const float*)d_in[3];
  const float* nb   = (const float*)d_in[4];
  const float* mW1  = (const float*)d_in[5];
  const float* mb1  = (const float*)d_in[6];
  const float* mW2  = (const float*)d_in[7];
  const float* mb2  = (const float*)d_in[8];
  const float* uW1  = (const float*)d_in[9];
  const float* ub1  = (const float*)d_in[10];
  const float* uW2  = (const float*)d_in[11];
  const float* ub2  = (const float*)d_in[12];
  const float* oW   = (const float*)d_in[13];
  const float* ob   = (const float*)d_in[14];
  float* out = (float*)d_out;

  char* ws = (char*)d_ws;
  size_t off = 0;
  f16* URa  = (f16*)(ws + off); off += (size_t)NN*512*2;
  f16* URb  = (f16*)(ws + off); off += (size_t)NN*512*2;
  f16* BtA  = (f16*)(ws + off); off += 6*512*256*2;
  f16* BtPQ = (f16*)(ws + off); off += 6*512*256*2;   // slot 0 unused
  f16* BtU  = (f16*)(ws + off); off += 6*256*512*2;
  f16* uW2h = (f16*)(ws + off); off += 6*256*256*2;
  f16* mW2h = (f16*)(ws + off); off += 6*256*256*2;
  f16* uW1aT= (f16*)(ws + off); off += 6*256*256*2;
  f16* uW1bT= (f16*)(ws + off); off += 6*256*256*2;
  f16* oWTh = (f16*)(ws + off); off += 128*256*2;
  f16* Wp2t = (f16*)(ws + off); off += 128*256*2;
  float* cvec = (float*)(ws + off); off += 6*4*256*4;
  float* wsi_ = (float*)(ws + off); off += 6*256*4;
  float* wsj_ = (float*)(ws + off); off += 6*256*4;
  float* v2   = (float*)(ws + off); off += 6*256*4;
  float* ubias= (float*)(ws + off); off += 6*256*4;
  float* pqb  = (float*)(ws + off); off += 6*512*4;   // slot 0 unused
  float* pa   = (float*)(ws + off); off += 512*4;
  float* pc   = (float*)(ws + off); off += 512*4;
  float* avec = (float*)(ws + off); off += 256*4;
  float* ob2  = (float*)(ws + off); off += 16*4;

  // ---- prep: casts & transposes (all coalesced) ----
  tcast256<<<dim3(8,8,6),256,0,stream>>>(mW1,          516*256, BtA,          131072); // W1a^T
  tcast256<<<dim3(8,8,6),256,0,stream>>>(mW1 + 65536,  516*256, BtA + 65536,  131072); // W1b^T
  tcast256<<<dim3(8,8,6),256,0,stream>>>(uW1,          131072,  uW1aT,        65536);
  tcast256<<<dim3(8,8,6),256,0,stream>>>(uW1 + 65536,  131072,  uW1bT,        65536);
  castw   <<<1536,256,0,stream>>>(uW2, mW2, uW2h, mW2h);
  prep_owt<<<128, 256,0,stream>>>(oW, oWTh);
  prep_cw <<<6,   256,0,stream>>>(mW1, mb1, cvec, wsi_, wsj_);
  prep_vecB<<<24, 256,0,stream>>>(mb2, uW1, ub1, ub2, nb, nW, v2, ubias, avec);
  prep_pqb2<<<48, 256,0,stream>>>(mW1, ub2, nW, nb, pqb, pa, pc);
  prep_ob2<<<1,   256,0,stream>>>(ub2, oW, ob, ob2);

  // ---- prep: weight folds via MFMA ----
  // BtPQ[l] = BtA[l] @ uW2h[l-1]^T   (layers 1..5)
  gemm_bt<256,0><<<dim3(4,2,5),256,0,stream>>>(
      BtA + 131072, 256, 131072, uW2h, 256, 65536,
      BtPQ + 131072, 256, 131072, nullptr, nullptr, nullptr, nullptr);
  // BtU[l] first half = uW1aT[l] @ uW2h[l-1]^T  (layers 1..5, ldc 512)
  gemm_bt<256,0><<<dim3(2,2,5),256,0,stream>>>(
      uW1aT + 65536, 256, 65536, uW2h, 256, 65536,
      BtU + 131072, 512, 131072, nullptr, nullptr, nullptr, nullptr);
  // BtU[l] second half = uW1bT[l] @ mW2h[l]^T = (mW2@uW1b)^T  (all 6 layers)
  gemm_bt<256,0><<<dim3(2,2,6),256,0,stream>>>(
      uW1bT, 256, 65536, mW2h, 256, 65536,
      BtU + 256, 512, 131072, nullptr, nullptr, nullptr, nullptr);
  // Wp2t = oWTh @ uW2h[5]^T   ([128][256])
  gemm_bt<256,0><<<dim3(1,2,1),256,0,stream>>>(
      oWTh, 256, 0, uW2h + 5*65536, 256, 0,
      Wp2t, 256, 0, nullptr, nullptr, nullptr, nullptr);

  // ---- layer 1 (rank-1 input, P/Q analytic) ----
  edge_fuse<1><<<8192,256,0,stream>>>(nullptr, URa, cvec, wsi_, wsj_, gridv, pa, pc);
  gemm_bt<256,3><<<dim3(512,2),256,0,stream>>>(
      URa + 256, 512, 0, BtU + 256, 512, 0, URa, 512, 0,
      ubias, v2, avec, gridv);

  // ---- layers 2..6 ----
  f16* cur = URa; f16* nxt = URb;
  for (int l=1;l<NL;l++){
    gemm_bt<256,2><<<dim3(512,4),256,0,stream>>>(
        cur, 512, 0, BtPQ + (size_t)l*131072, 256, 0, nxt, 512, 0,
        pqb + l*512, nullptr, nullptr, nullptr);
    edge_fuse<0><<<8192,256,0,stream>>>(nxt, cur, cvec + l*1024, wsi_ + l*256, wsj_ + l*256,
                                        nullptr, nullptr, nullptr);
    gemm_bt<512,1><<<dim3(512,2),256,0,stream>>>(
        cur, 512, 0, BtU + (size_t)l*131072, 512, 0, nxt, 512, 0,
        ubias + l*256, v2 + l*256, nullptr, nullptr);
    f16* t = cur; cur = nxt; nxt = t;
  }

  // out = U6 @ Wp2t^T + ob2
  out_mfma<<<1024,256,0,stream>>>(cur, Wp2t, ob2, out);
}

// Round 4
// 582.688 us; speedup vs baseline: 1.3165x; 1.0533x over previous
//
#include <hip/hip_runtime.h>

#define HG 256
#define WGD 256
#define NN (HG*WGD)
#define NL 6

typedef _Float16 f16;
typedef _Float16 f16x8 __attribute__((ext_vector_type(8)));
typedef float f32x4 __attribute__((ext_vector_type(4)));

__device__ __forceinline__ void gload_lds16(const f16* g, f16* lds) {
  __builtin_amdgcn_global_load_lds(
      (const __attribute__((address_space(1))) unsigned int*)g,
      (__attribute__((address_space(3))) unsigned int*)lds, 16, 0, 0);
}

// C[M,N] = A[M,KK] @ Bt[N,KK]^T  (f16 in, f32 accum, f16 out), z-batched.
// LDS tiles XOR-swizzled (T2): 16B block b of row r lives at physical block
// b^(r&7). Staged via pre-swizzled GLOBAL source (LDS dest linear, m104/m173);
// read back with the same XOR. In the fragment read row&7 == lane&7.
// EPI: 0 plain | 1 +bias[col]+deg(row)*v2[col], relu | 2 +bias[col]
//      3 +bias[col]+deg*v2[col]+g[row]*avec[col], relu   (layer-1 update)
template<int KK, int EPI>
__global__ __launch_bounds__(256) void gemm_bt(
    const f16* __restrict__ A, int lda, size_t asb,
    const f16* __restrict__ Bt, int ldb, size_t bsb,
    f16* __restrict__ C, int ldc, size_t csb,
    const float* __restrict__ bias,
    const float* __restrict__ v2,
    const float* __restrict__ avec,
    const int* __restrict__ gridv)
{
  A  += blockIdx.z * asb;
  Bt += blockIdx.z * bsb;
  C  += blockIdx.z * csb;

  __shared__ f16 As[128*64];
  __shared__ f16 Bs[128*64];
  const int tid  = threadIdx.x;
  const int lane = tid & 63;
  const int w    = tid >> 6;
  const int wm   = w >> 1, wn = w & 1;
  const int mbase = blockIdx.x * 128;
  const int nbase = blockIdx.y * 128;

  f32x4 acc[4][4];
#pragma unroll
  for (int a=0;a<4;a++)
#pragma unroll
    for (int b=0;b<4;b++) acc[a][b] = (f32x4){0.f,0.f,0.f,0.f};

  const int r8  = lane >> 3;                    // row within 8-row stage group
  const int c8s = ((lane & 7) ^ r8) * 8;        // pre-swizzled source col (f16)

  for (int kt = 0; kt < KK/64; ++kt) {
    const f16* Ab = A  + (size_t)(mbase + w*32)*lda + kt*64;
    const f16* Bb = Bt + (size_t)(nbase + w*32)*ldb + kt*64;
#pragma unroll
    for (int i=0;i<4;i++) {
      gload_lds16(Ab + (size_t)(i*8 + r8)*lda + c8s, &As[(w*32+i*8)*64]);
      gload_lds16(Bb + (size_t)(i*8 + r8)*ldb + c8s, &Bs[(w*32+i*8)*64]);
    }
    __syncthreads();
#pragma unroll
    for (int ks=0; ks<2; ++ks) {
      // swizzled read offset: logical block b = ks*4 + (lane>>4), row&7 = lane&7
      const int off = (((ks*4 + (lane>>4)) ^ (lane & 7)) * 8);
      f16x8 af[4], bf[4];
#pragma unroll
      for (int fm=0; fm<4; ++fm)
        af[fm] = *(const f16x8*)&As[(wm*64 + fm*16 + (lane&15))*64 + off];
#pragma unroll
      for (int fn=0; fn<4; ++fn)
        bf[fn] = *(const f16x8*)&Bs[(wn*64 + fn*16 + (lane&15))*64 + off];
#pragma unroll
      for (int fm=0; fm<4; ++fm)
#pragma unroll
        for (int fn=0; fn<4; ++fn)
          acc[fm][fn] = __builtin_amdgcn_mfma_f32_16x16x32_f16(af[fm], bf[fn], acc[fm][fn], 0,0,0);
    }
    __syncthreads();
  }

  const int row0 = mbase + wm*64 + (lane>>4)*4;
  const int col0 = nbase + wn*64 + (lane&15);
#pragma unroll
  for (int fm=0; fm<4; ++fm) {
#pragma unroll
    for (int fn=0; fn<4; ++fn) {
      const int col = col0 + fn*16;
#pragma unroll
      for (int r=0;r<4;r++) {
        int row = row0 + fm*16 + r;
        float v = acc[fm][fn][r];
        if (EPI==1 || EPI==3) {
          int i = row >> 8, j = row & 255;
          float deg = (float)((i>0)+(i<255)+(j>0)+(j<255));
          v += bias[col] + deg * v2[col];
          if (EPI==3) v += (float)gridv[row] * avec[col];
          v = fmaxf(v, 0.f);
        } else if (EPI==2) {
          v += bias[col];
        }
        C[(size_t)row*ldc + col] = (f16)v;
      }
    }
  }
}

// R[n] = sum over valid dirs of relu(P[src]+Q[n]+cvec_d+(si/256)*wsi+(sj/256)*wsj)
// R1=0: PQ [N,512] cols 0..255 = P, 256..511 = Q.
// R1=1: P/Q analytic from g (rank-1 layer 1).
template<int R1>
__global__ __launch_bounds__(256) void edge_fuse(
    const f16* __restrict__ PQ, f16* __restrict__ UR,
    const float* __restrict__ cvec, const float* __restrict__ wsi_,
    const float* __restrict__ wsj_,
    const int* __restrict__ gridv, const float* __restrict__ pa,
    const float* __restrict__ pc)
{
  const int t  = threadIdx.x;
  const int ln = t >> 5, ch = t & 31;
  const int n  = blockIdx.x*8 + ln;
  const int i  = n >> 8, j = n & 255;
  const int co = ch*8;

  float q[8], pa0[8], pc0[8];
  if (R1) {
    float g = (float)gridv[n];
#pragma unroll
    for (int e=0;e<8;e++) {
      pa0[e] = pa[co+e]; pc0[e] = pc[co+e];
      q[e] = g*pa[256+co+e] + pc[256+co+e];
    }
  } else {
    f16x8 qv = *(const f16x8*)&PQ[(size_t)n*512 + 256 + co];
#pragma unroll
    for (int e=0;e<8;e++) q[e] = (float)qv[e];
  }
  float wi[8], wj[8];
#pragma unroll
  for (int e=0;e<8;e++){ wi[e]=wsi_[co+e]; wj[e]=wsj_[co+e]; }
  float acc[8];
#pragma unroll
  for (int e=0;e<8;e++) acc[e]=0.f;

  const int DI[4] = {-1,1,0,0};
  const int DJ[4] = {0,0,-1,1};
#pragma unroll
  for (int d=0; d<4; ++d) {
    int si = i - DI[d], sj = j - DJ[d];
    if (si>=0 && si<HG && sj>=0 && sj<WGD) {
      int s = si*WGD + sj;
      float fsi = si * (1.f/HG), fsj = sj * (1.f/WGD);
      float pvf[8];
      if (R1) {
        float gs = (float)gridv[s];
#pragma unroll
        for (int e=0;e<8;e++) pvf[e] = gs*pa0[e] + pc0[e];
      } else {
        f16x8 pv = *(const f16x8*)&PQ[(size_t)s*512 + co];
#pragma unroll
        for (int e=0;e<8;e++) pvf[e] = (float)pv[e];
      }
#pragma unroll
      for (int e=0;e<8;e++) {
        float v = pvf[e] + q[e] + cvec[d*256+co+e] + fsi*wi[e] + fsj*wj[e];
        acc[e] += fmaxf(v, 0.f);
      }
    }
  }
  f16x8 outv;
#pragma unroll
  for (int e=0;e<8;e++) outv[e] = (f16)acc[e];
  *(f16x8*)&UR[(size_t)n*512 + 256 + co] = outv;
}

// out[n,0..9] = U6[n,:] @ Wp2t^T + ob2  via MFMA, 1 wave = 16 nodes
__global__ __launch_bounds__(256) void out_mfma(
    const f16* __restrict__ U,        // lda 512
    const f16* __restrict__ Wp2t,     // [128][256], rows >=10 zero
    const float* __restrict__ ob2,
    float* __restrict__ out)
{
  int lane = threadIdx.x & 63;
  int wv   = threadIdx.x >> 6;
  int nbase = blockIdx.x*64 + wv*16;
  f32x4 acc = (f32x4){0.f,0.f,0.f,0.f};
  int r  = lane & 15;
  int kg = (lane >> 4) * 8;
  const f16* Up = U + (size_t)(nbase + r)*512 + kg;
  const f16* Bp = Wp2t + r*256 + kg;
#pragma unroll
  for (int kt=0; kt<8; ++kt) {
    f16x8 af = *(const f16x8*)(Up + kt*32);
    f16x8 bf = *(const f16x8*)(Bp + kt*32);
    acc = __builtin_amdgcn_mfma_f32_16x16x32_f16(af, bf, acc, 0,0,0);
  }
  int col = lane & 15;
  int row0 = (lane>>4)*4;
  if (col < 10) {
    float bo = ob2[col];
#pragma unroll
    for (int rr=0; rr<4; ++rr)
      out[(size_t)(nbase + row0 + rr)*10 + col] = acc[rr] + bo;
  }
}

// ---- prep: LDS-tiled 256x256 transpose-cast, z-batched ----
__global__ __launch_bounds__(256) void tcast256(
    const float* __restrict__ src, size_t sls,
    f16* __restrict__ dst, size_t dls)
{
  __shared__ float tbuf[32][33];
  const int l = blockIdx.z;
  const int bc = blockIdx.x*32;
  const int br = blockIdx.y*32;
  const int tx = threadIdx.x & 31, ty = threadIdx.x >> 5;
  const float* s = src + (size_t)l*sls;
  f16* d = dst + (size_t)l*dls;
#pragma unroll
  for (int rr=0; rr<4; ++rr)
    tbuf[ty+rr*8][tx] = s[(size_t)(br+ty+rr*8)*256 + bc+tx];
  __syncthreads();
#pragma unroll
  for (int rr=0; rr<4; ++rr)
    d[(size_t)(bc+ty+rr*8)*256 + br+tx] = (f16)tbuf[tx][ty+rr*8];
}

__global__ __launch_bounds__(256) void castw(
    const float* __restrict__ uW2, const float* __restrict__ mW2,
    f16* __restrict__ uW2h, f16* __restrict__ mW2h)
{
  int idx = blockIdx.x*256+threadIdx.x;
  uW2h[idx] = (f16)uW2[idx];
  mW2h[idx] = (f16)mW2[idx];
}

__global__ __launch_bounds__(256) void prep_owt(const float* __restrict__ oW, f16* __restrict__ oWTh){
  int c = blockIdx.x, j = threadIdx.x;
  oWTh[c*256 + j] = (c < 10) ? (f16)oW[j*10 + c] : (f16)0.f;
}

__global__ __launch_bounds__(256) void prep_cw(
    const float* __restrict__ mW1, const float* __restrict__ mb1,
    float* __restrict__ cvec, float* __restrict__ wsi_, float* __restrict__ wsj_)
{
  int l = blockIdx.x, j = threadIdx.x;
  const float* base = mW1 + (size_t)l*516*256;
  float w512 = base[512*256 + j], w513 = base[513*256 + j];
  float b1 = mb1[l*256 + j];
  const int DI[4] = {-1,1,0,0};
  const int DJ[4] = {0,0,-1,1};
  for (int d=0;d<4;d++)
    cvec[(l*4+d)*256 + j] = (float)DI[d]*w512 + (float)DJ[d]*w513 + b1;
  wsi_[l*256+j] = base[514*256 + j];
  wsj_[l*256+j] = base[515*256 + j];
}

__global__ __launch_bounds__(256) void prep_vecB(
    const float* __restrict__ mb2, const float* __restrict__ uW1,
    const float* __restrict__ ub1, const float* __restrict__ ub2,
    const float* __restrict__ nb,  const float* __restrict__ nW,
    float* __restrict__ v2, float* __restrict__ ubias, float* __restrict__ avec)
{
  __shared__ float red[3][4][64];
  int pr = threadIdx.x & 63, q = threadIdx.x >> 6;
  int pair = blockIdx.x*64 + pr;
  int l = pair >> 8, j = pair & 255;
  const float* prevb = l ? (ub2 + (l-1)*256) : nb;
  float s1=0.f, s2=0.f, s3=0.f;
  for (int t = q*64; t < q*64+64; ++t) {
    s1 += mb2[l*256+t] * uW1[((size_t)l*512+256+t)*256 + j];
    s2 += prevb[t]     * uW1[((size_t)l*512+t)*256 + j];
    if (l==0) s3 += nW[t] * uW1[(size_t)t*256 + j];
  }
  red[0][q][pr]=s1; red[1][q][pr]=s2; red[2][q][pr]=s3;
  __syncthreads();
  if (q==0) {
    float a = red[0][0][pr]+red[0][1][pr]+red[0][2][pr]+red[0][3][pr];
    float b = red[1][0][pr]+red[1][1][pr]+red[1][2][pr]+red[1][3][pr];
    v2[pair] = a;
    ubias[pair] = ub1[pair] + b;
    if (l==0) avec[j] = red[2][0][pr]+red[2][1][pr]+red[2][2][pr]+red[2][3][pr];
  }
}

__global__ __launch_bounds__(256) void prep_pqb2(
    const float* __restrict__ mW1, const float* __restrict__ ub2,
    const float* __restrict__ nW,  const float* __restrict__ nb,
    float* __restrict__ pqb, float* __restrict__ pa, float* __restrict__ pc)
{
  __shared__ float red[2][4][64];
  int pr = threadIdx.x & 63, q = threadIdx.x >> 6;
  int pair = blockIdx.x*64 + pr;
  int l = pair >> 9, c = pair & 511;
  int rowoff = (c < 256) ? 0 : 256;
  int cc = c & 255;
  const float* base = mW1 + (size_t)l*516*256 + (size_t)rowoff*256 + cc;
  float s1=0.f, s2=0.f;
  if (l==0) {
    for (int j=q*64; j<q*64+64; ++j) { float wv = base[(size_t)j*256]; s1 += nW[j]*wv; s2 += nb[j]*wv; }
  } else {
    const float* pb = ub2 + (l-1)*256;
    for (int j=q*64; j<q*64+64; ++j) s1 += pb[j]*base[(size_t)j*256];
  }
  red[0][q][pr]=s1; red[1][q][pr]=s2;
  __syncthreads();
  if (q==0) {
    float a = red[0][0][pr]+red[0][1][pr]+red[0][2][pr]+red[0][3][pr];
    if (l==0) { pa[c]=a; pc[c]=red[1][0][pr]+red[1][1][pr]+red[1][2][pr]+red[1][3][pr]; }
    else pqb[pair] = a;
  }
}

__global__ __launch_bounds__(256) void prep_ob2(
    const float* __restrict__ ub2, const float* __restrict__ oW,
    const float* __restrict__ ob, float* __restrict__ ob2)
{
  __shared__ float red[16][16];
  int c = threadIdx.x >> 4, jg = threadIdx.x & 15;
  float s = 0.f;
  if (c < 10)
    for (int j=jg*16; j<jg*16+16; ++j) s += ub2[5*256+j]*oW[j*10+c];
  red[c][jg] = s;
  __syncthreads();
  if (jg==0) {
    float a=0.f;
    for (int t2=0;t2<16;t2++) a += red[c][t2];
    ob2[c] = (c < 10) ? a + ob[c] : 0.f;
  }
}

extern "C" void kernel_launch(void* const* d_in, const int* in_sizes, int n_in,
                              void* d_out, int out_size, void* d_ws, size_t ws_size,
                              hipStream_t stream)
{
  const int*   gridv = (const int*) d_in[0];
  const float* nW   = (const float*)d_in[3];
  const float* nb   = (const float*)d_in[4];
  const float* mW1  = (const float*)d_in[5];
  const float* mb1  = (const float*)d_in[6];
  const float* mW2  = (const float*)d_in[7];
  const float* mb2  = (const float*)d_in[8];
  const float* uW1  = (const float*)d_in[9];
  const float* ub1  = (const float*)d_in[10];
  const float* uW2  = (const float*)d_in[11];
  const float* ub2  = (const float*)d_in[12];
  const float* oW   = (const float*)d_in[13];
  const float* ob   = (const float*)d_in[14];
  float* out = (float*)d_out;

  char* ws = (char*)d_ws;
  size_t off = 0;
  f16* URa  = (f16*)(ws + off); off += (size_t)NN*512*2;
  f16* URb  = (f16*)(ws + off); off += (size_t)NN*512*2;
  f16* BtA  = (f16*)(ws + off); off += 6*512*256*2;
  f16* BtPQ = (f16*)(ws + off); off += 6*512*256*2;   // slot 0 unused
  f16* BtU  = (f16*)(ws + off); off += 6*256*512*2;
  f16* uW2h = (f16*)(ws + off); off += 6*256*256*2;
  f16* mW2h = (f16*)(ws + off); off += 6*256*256*2;
  f16* uW1aT= (f16*)(ws + off); off += 6*256*256*2;
  f16* uW1bT= (f16*)(ws + off); off += 6*256*256*2;
  f16* oWTh = (f16*)(ws + off); off += 128*256*2;
  f16* Wp2t = (f16*)(ws + off); off += 128*256*2;
  float* cvec = (float*)(ws + off); off += 6*4*256*4;
  float* wsi_ = (float*)(ws + off); off += 6*256*4;
  float* wsj_ = (float*)(ws + off); off += 6*256*4;
  float* v2   = (float*)(ws + off); off += 6*256*4;
  float* ubias= (float*)(ws + off); off += 6*256*4;
  float* pqb  = (float*)(ws + off); off += 6*512*4;   // slot 0 unused
  float* pa   = (float*)(ws + off); off += 512*4;
  float* pc   = (float*)(ws + off); off += 512*4;
  float* avec = (float*)(ws + off); off += 256*4;
  float* ob2  = (float*)(ws + off); off += 16*4;

  // ---- prep: casts & transposes ----
  tcast256<<<dim3(8,8,6),256,0,stream>>>(mW1,          516*256, BtA,          131072);
  tcast256<<<dim3(8,8,6),256,0,stream>>>(mW1 + 65536,  516*256, BtA + 65536,  131072);
  tcast256<<<dim3(8,8,6),256,0,stream>>>(uW1,          131072,  uW1aT,        65536);
  tcast256<<<dim3(8,8,6),256,0,stream>>>(uW1 + 65536,  131072,  uW1bT,        65536);
  castw   <<<1536,256,0,stream>>>(uW2, mW2, uW2h, mW2h);
  prep_owt<<<128, 256,0,stream>>>(oW, oWTh);
  prep_cw <<<6,   256,0,stream>>>(mW1, mb1, cvec, wsi_, wsj_);
  prep_vecB<<<24, 256,0,stream>>>(mb2, uW1, ub1, ub2, nb, nW, v2, ubias, avec);
  prep_pqb2<<<48, 256,0,stream>>>(mW1, ub2, nW, nb, pqb, pa, pc);
  prep_ob2<<<1,   256,0,stream>>>(ub2, oW, ob, ob2);

  // ---- prep: weight folds via MFMA ----
  gemm_bt<256,0><<<dim3(4,2,5),256,0,stream>>>(
      BtA + 131072, 256, 131072, uW2h, 256, 65536,
      BtPQ + 131072, 256, 131072, nullptr, nullptr, nullptr, nullptr);
  gemm_bt<256,0><<<dim3(2,2,5),256,0,stream>>>(
      uW1aT + 65536, 256, 65536, uW2h, 256, 65536,
      BtU + 131072, 512, 131072, nullptr, nullptr, nullptr, nullptr);
  gemm_bt<256,0><<<dim3(2,2,6),256,0,stream>>>(
      uW1bT, 256, 65536, mW2h, 256, 65536,
      BtU + 256, 512, 131072, nullptr, nullptr, nullptr, nullptr);
  gemm_bt<256,0><<<dim3(1,2,1),256,0,stream>>>(
      oWTh, 256, 0, uW2h + 5*65536, 256, 0,
      Wp2t, 256, 0, nullptr, nullptr, nullptr, nullptr);

  // ---- layer 1 (rank-1 input, P/Q analytic) ----
  edge_fuse<1><<<8192,256,0,stream>>>(nullptr, URa, cvec, wsi_, wsj_, gridv, pa, pc);
  gemm_bt<256,3><<<dim3(512,2),256,0,stream>>>(
      URa + 256, 512, 0, BtU + 256, 512, 0, URa, 512, 0,
      ubias, v2, avec, gridv);

  // ---- layers 2..6 ----
  f16* cur = URa; f16* nxt = URb;
  for (int l=1;l<NL;l++){
    gemm_bt<256,2><<<dim3(512,4),256,0,stream>>>(
        cur, 512, 0, BtPQ + (size_t)l*131072, 256, 0, nxt, 512, 0,
        pqb + l*512, nullptr, nullptr, nullptr);
    edge_fuse<0><<<8192,256,0,stream>>>(nxt, cur, cvec + l*1024, wsi_ + l*256, wsj_ + l*256,
                                        nullptr, nullptr, nullptr);
    gemm_bt<512,1><<<dim3(512,2),256,0,stream>>>(
        cur, 512, 0, BtU + (size_t)l*131072, 512, 0, nxt, 512, 0,
        ubias + l*256, v2 + l*256, nullptr, nullptr);
    f16* t = cur; cur = nxt; nxt = t;
  }

  // out = U6 @ Wp2t^T + ob2
  out_mfma<<<1024,256,0,stream>>>(cur, Wp2t, ob2, out);
}